// Round 3
// baseline (1227.507 us; speedup 1.0000x reference)
//
#include <hip/hip_runtime.h>

// GCN forward: mid = relu(spmm(A, x@W1) + b1); out = spmm(A, mid@W2) + b2
// N=100000, F=512, H=256, C=40, E=3.2M.
//
// R3 changes vs R2:
//  - spmm1 split into two feature-half passes (cols 0-127 / 128-255): halves the
//    gather working set per pass (25.6 MB) for better L2 temporal hit rate, and
//    splits the dominant dispatch so the profile exposes other kernels.
//  - gemm1: BM=128 (2 row-tiles per wave) -> 32 MFMA per 18 ds_read_b128.
//  - CSR: row_ptr doubles as scatter cursor (exclusive prefix at index i;
//    after scatter rp[r] = end(r), start(r) = r ? rp[r-1] : 0). cursor array,
//    its memset, and scatter's row_ptr read removed. hist int4-vectorized.
//  - spmm2: lane-split int4 edge loads (1 load / 4 edges), no cndmask selects.

typedef __bf16 bf16;
typedef __bf16 bf16x8 __attribute__((ext_vector_type(8)));
typedef float floatx4 __attribute__((ext_vector_type(4)));

__device__ __forceinline__ float bflo(unsigned int u) { return __uint_as_float(u << 16); }
__device__ __forceinline__ float bfhi(unsigned int u) { return __uint_as_float(u & 0xffff0000u); }

// ---------------- weight conversion ----------------
__global__ __launch_bounds__(256) void conv_w(const float* __restrict__ W1,
                                              const float* __restrict__ W2,
                                              bf16* __restrict__ W1T,
                                              bf16* __restrict__ W2T) {
  int i = blockIdx.x * 256 + threadIdx.x;
  if (i < 512 * 256) {             // W1 [512][256] -> W1T [256][512]
    int k = i >> 8, n = i & 255;
    W1T[n * 512 + k] = (bf16)W1[i];
  }
  int j = i - 512 * 256;
  if (j >= 0 && j < 48 * 256) {    // W2 [256][40] -> W2T [48][256], pad rows 40..47
    int n = j >> 8, k = j & 255;
    W2T[j] = (n < 40) ? (bf16)W2[k * 40 + n] : (bf16)0.0f;
  }
}

// ---------------- CSR build ----------------
__global__ __launch_bounds__(256) void hist_kernel(const int* __restrict__ er,
                                                   int* __restrict__ counts, int E) {
  int i = (blockIdx.x * 256 + threadIdx.x) * 4;
  if (i + 3 < E) {
    int4 r = *(const int4*)(er + i);
    atomicAdd(&counts[r.x], 1);
    atomicAdd(&counts[r.y], 1);
    atomicAdd(&counts[r.z], 1);
    atomicAdd(&counts[r.w], 1);
  } else {
    for (int k = i; k < E; k++) atomicAdd(&counts[er[k]], 1);
  }
}

// single-block scan: rp[i] = exclusive prefix (start of row i)
__global__ __launch_bounds__(1024) void scan_kernel(const int* __restrict__ counts,
                                                    int* __restrict__ rp, int Nn) {
  __shared__ int wsum[16];
  const int t = threadIdx.x;
  const int wave = t >> 6, lane = t & 63;
  const int C = (((Nn + 1023) / 1024) + 3) & ~3;
  const int base = t * C;
  int s = 0;
  for (int k = 0; k < C; k += 4) {
    int gi = base + k;
    if (gi + 3 < Nn) {
      int4 v = *(const int4*)(counts + gi);
      s += v.x + v.y + v.z + v.w;
    } else {
      if (gi     < Nn) s += counts[gi];
      if (gi + 1 < Nn) s += counts[gi + 1];
      if (gi + 2 < Nn) s += counts[gi + 2];
      if (gi + 3 < Nn) s += counts[gi + 3];
    }
  }
  int incl = s;
#pragma unroll
  for (int d = 1; d < 64; d <<= 1) {
    int o = __shfl_up(incl, d, 64);
    if (lane >= d) incl += o;
  }
  if (lane == 63) wsum[wave] = incl;
  __syncthreads();
  int wave_off = 0;
#pragma unroll
  for (int w = 0; w < 16; w++) {
    int xw = wsum[w];
    if (w < wave) wave_off += xw;
  }
  int p = wave_off + (incl - s);
  for (int k = 0; k < C; k += 4) {
    int gi = base + k;
    int4 v = {0, 0, 0, 0};
    if (gi + 3 < Nn) {
      v = *(const int4*)(counts + gi);
    } else {
      if (gi     < Nn) v.x = counts[gi];
      if (gi + 1 < Nn) v.y = counts[gi + 1];
      if (gi + 2 < Nn) v.z = counts[gi + 2];
      if (gi + 3 < Nn) v.w = counts[gi + 3];
    }
    if (gi     < Nn) rp[gi]     = p; p += v.x;
    if (gi + 1 < Nn) rp[gi + 1] = p; p += v.y;
    if (gi + 2 < Nn) rp[gi + 2] = p; p += v.z;
    if (gi + 3 < Nn) rp[gi + 3] = p; p += v.w;
  }
}

// scatter: rp is the cursor; afterwards rp[r] = end of row r
__global__ __launch_bounds__(256) void scatter_kernel(
    const int* __restrict__ er, const int* __restrict__ ec, const float* __restrict__ ev,
    int* __restrict__ rp, int2* __restrict__ epack, int E) {
  int i = blockIdx.x * 256 + threadIdx.x;
  if (i < E) {
    int r = er[i];
    int p = atomicAdd(&rp[r], 1);
    int2 m;
    m.x = ec[i];
    m.y = __float_as_int(ev[i]);
    epack[p] = m;
  }
}

// ---------------- GEMM1: T1 = bf16(x @ W1), [M][256], BM=128 ----------------
__global__ __launch_bounds__(256) void gemm1_kernel(const float* __restrict__ x,
                                                    const bf16* __restrict__ W1T,
                                                    bf16* __restrict__ T1, int M) {
  __shared__ __align__(16) bf16 As[128][40];
  __shared__ __align__(16) bf16 Bs[256][40];
  const int t = threadIdx.x;
  const int wave = t >> 6, lane = t & 63;
  const int quad = lane >> 4, l16 = lane & 15;
  const int m0 = blockIdx.x * 128;
  floatx4 acc[2][16] = {};

  const int ar = t >> 1, ah = (t & 1) * 16;   // A staging: row ar, 16 floats at col ah
  const int a_gr = m0 + ar;
  const float* a_src = x + (size_t)a_gr * 512 + ah;
  const bf16* b_src = W1T + (size_t)t * 512;

  for (int k0 = 0; k0 < 512; k0 += 32) {
    __syncthreads();
    {  // stage A (fp32 -> bf16): 128 rows x 32 cols
      float4 f0 = {0,0,0,0}, f1 = {0,0,0,0}, f2 = {0,0,0,0}, f3 = {0,0,0,0};
      if (a_gr < M) {
        const float4* p = (const float4*)(a_src + k0);
        f0 = p[0]; f1 = p[1]; f2 = p[2]; f3 = p[3];
      }
      bf16x8 av0, av1;
      av0[0] = (bf16)f0.x; av0[1] = (bf16)f0.y; av0[2] = (bf16)f0.z; av0[3] = (bf16)f0.w;
      av0[4] = (bf16)f1.x; av0[5] = (bf16)f1.y; av0[6] = (bf16)f1.z; av0[7] = (bf16)f1.w;
      av1[0] = (bf16)f2.x; av1[1] = (bf16)f2.y; av1[2] = (bf16)f2.z; av1[3] = (bf16)f2.w;
      av1[4] = (bf16)f3.x; av1[5] = (bf16)f3.y; av1[6] = (bf16)f3.z; av1[7] = (bf16)f3.w;
      *(bf16x8*)&As[ar][ah]     = av0;
      *(bf16x8*)&As[ar][ah + 8] = av1;
    }
    {  // stage B: thread t owns row n=t (32 bf16)
      const bf16* p = b_src + k0;
      bf16x8 q0 = *(const bf16x8*)(p);
      bf16x8 q1 = *(const bf16x8*)(p + 8);
      bf16x8 q2 = *(const bf16x8*)(p + 16);
      bf16x8 q3 = *(const bf16x8*)(p + 24);
      *(bf16x8*)&Bs[t][0]  = q0;
      *(bf16x8*)&Bs[t][8]  = q1;
      *(bf16x8*)&Bs[t][16] = q2;
      *(bf16x8*)&Bs[t][24] = q3;
    }
    __syncthreads();
    bf16x8 a0 = *(const bf16x8*)&As[wave * 32 + l16][quad * 8];
    bf16x8 a1 = *(const bf16x8*)&As[wave * 32 + 16 + l16][quad * 8];
#pragma unroll
    for (int nt = 0; nt < 16; nt++) {
      bf16x8 b = *(const bf16x8*)&Bs[nt * 16 + l16][quad * 8];
      acc[0][nt] = __builtin_amdgcn_mfma_f32_16x16x32_bf16(a0, b, acc[0][nt], 0, 0, 0);
      acc[1][nt] = __builtin_amdgcn_mfma_f32_16x16x32_bf16(a1, b, acc[1][nt], 0, 0, 0);
    }
  }
#pragma unroll
  for (int rt = 0; rt < 2; rt++) {
    const int row_base = m0 + wave * 32 + rt * 16 + quad * 4;
#pragma unroll
    for (int nt = 0; nt < 16; nt++) {
#pragma unroll
      for (int j = 0; j < 4; j++) {
        int gr = row_base + j;
        if (gr < M) T1[(size_t)gr * 256 + nt * 16 + l16] = (bf16)acc[rt][nt][j];
      }
    }
  }
}

// ---------------- SpMM1 (per feature-half): mid[:, col0:col0+128] ----------------
__global__ __launch_bounds__(256) void spmm1_kernel(
    const int* __restrict__ rp, const int2* __restrict__ epack,
    const unsigned int* __restrict__ T1u, const float* __restrict__ b1,
    float* __restrict__ mid, int M, int col0) {
  const int lane = threadIdx.x & 63;
  const int r = blockIdx.x * 4 + (threadIdx.x >> 6);
  if (r >= M) return;
  const int eend = rp[r];
  int e = (r == 0) ? 0 : rp[r - 1];
  float a0 = 0.f, a1 = 0.f;
  const unsigned int* base = T1u + (col0 >> 1) + lane;  // 2 bf16 per lane, stride 128 uints
  if (e < eend && (e & 1)) {  // align to even for int4 loads
    int2 m = epack[e];
    float v = __int_as_float(m.y);
    unsigned int u = base[(size_t)m.x * 128];
    a0 += v * bflo(u); a1 += v * bfhi(u);
    e++;
  }
  for (; e + 3 < eend; e += 4) {
    int4 p01 = *(const int4*)(epack + e);
    int4 p23 = *(const int4*)(epack + e + 2);
    unsigned int u0 = base[(size_t)p01.x * 128];
    unsigned int u1 = base[(size_t)p01.z * 128];
    unsigned int u2 = base[(size_t)p23.x * 128];
    unsigned int u3 = base[(size_t)p23.z * 128];
    float v0 = __int_as_float(p01.y), v1 = __int_as_float(p01.w);
    float v2 = __int_as_float(p23.y), v3 = __int_as_float(p23.w);
    a0 += v0 * bflo(u0); a1 += v0 * bfhi(u0);
    a0 += v1 * bflo(u1); a1 += v1 * bfhi(u1);
    a0 += v2 * bflo(u2); a1 += v2 * bfhi(u2);
    a0 += v3 * bflo(u3); a1 += v3 * bfhi(u3);
  }
  for (; e < eend; e++) {
    int2 m = epack[e];
    float v = __int_as_float(m.y);
    unsigned int u = base[(size_t)m.x * 128];
    a0 += v * bflo(u); a1 += v * bfhi(u);
  }
  int c = col0 + lane * 2;
  float2 bb = *(const float2*)(b1 + c);
  float2 o;
  o.x = fmaxf(a0 + bb.x, 0.f);
  o.y = fmaxf(a1 + bb.y, 0.f);
  *(float2*)(mid + (size_t)r * 256 + c) = o;
}

// ---------------- GEMM2: T2p = bf16(mid @ W2), [M][64] (cols 0..39 valid) ----------------
__global__ __launch_bounds__(256) void gemm2_kernel(const float* __restrict__ mid,
                                                    const bf16* __restrict__ W2T,
                                                    bf16* __restrict__ T2p, int M) {
  __shared__ __align__(16) bf16 As[64][40];
  __shared__ __align__(16) bf16 Bs[48][40];
  const int t = threadIdx.x;
  const int wave = t >> 6, lane = t & 63;
  const int quad = lane >> 4, l16 = lane & 15;
  const int m0 = blockIdx.x * 64;
  floatx4 acc[3] = {};
  const int ar = t >> 2, aq = t & 3;
  const int a_gr = m0 + ar;
  const float* a_src = mid + (size_t)a_gr * 256 + aq * 8;

  for (int k0 = 0; k0 < 256; k0 += 32) {
    __syncthreads();
    {
      float4 f0 = {0,0,0,0}, f1 = {0,0,0,0};
      if (a_gr < M) {
        const float4* p = (const float4*)(a_src + k0);
        f0 = p[0]; f1 = p[1];
      }
      bf16x8 av;
      av[0] = (bf16)f0.x; av[1] = (bf16)f0.y; av[2] = (bf16)f0.z; av[3] = (bf16)f0.w;
      av[4] = (bf16)f1.x; av[5] = (bf16)f1.y; av[6] = (bf16)f1.z; av[7] = (bf16)f1.w;
      *(bf16x8*)&As[ar][aq * 8] = av;
    }
    if (t < 192) {
      int n = t >> 2, q = t & 3;
      bf16x8 b = *(const bf16x8*)(W2T + n * 256 + k0 + q * 8);
      *(bf16x8*)&Bs[n][q * 8] = b;
    }
    __syncthreads();
    bf16x8 a = *(const bf16x8*)&As[wave * 16 + l16][quad * 8];
#pragma unroll
    for (int nt = 0; nt < 3; nt++) {
      bf16x8 b = *(const bf16x8*)&Bs[nt * 16 + l16][quad * 8];
      acc[nt] = __builtin_amdgcn_mfma_f32_16x16x32_bf16(a, b, acc[nt], 0, 0, 0);
    }
  }
  const int row_base = m0 + wave * 16 + quad * 4;
#pragma unroll
  for (int nt = 0; nt < 3; nt++) {
#pragma unroll
    for (int j = 0; j < 4; j++) {
      int gr = row_base + j;
      int col = nt * 16 + l16;
      if (gr < M && col < 40) T2p[(size_t)gr * 64 + col] = (bf16)acc[nt][j];
    }
  }
}

// ---------------- SpMM2: out = gather-sum(T2p) + b2 ----------------
// half-wave per edge: lanes 0..31 own edges e,e+1; lanes 32..63 own e+2,e+3.
__global__ __launch_bounds__(256) void spmm2_kernel(
    const int* __restrict__ rp, const int2* __restrict__ epack,
    const unsigned int* __restrict__ T2u,  // bf16 rows, stride 32 uints (128B)
    const float* __restrict__ b2, float* __restrict__ out2, int M) {
  const int lane = threadIdx.x & 63;
  const int r = blockIdx.x * 4 + (threadIdx.x >> 6);
  if (r >= M) return;
  const int l31 = lane & 31;
  const int half = lane >> 5;
  const int eend = rp[r];
  int e = (r == 0) ? 0 : rp[r - 1];
  float a0 = 0.f, a1 = 0.f;
  const unsigned int* base = T2u + l31;
  if (e < eend && (e & 1)) {  // align; half0 only
    if (half == 0) {
      int2 m = epack[e];
      float v = __int_as_float(m.y);
      unsigned int u = base[(size_t)m.x * 32];
      a0 += v * bflo(u); a1 += v * bfhi(u);
    }
    e++;
  }
  for (; e + 3 < eend; e += 4) {
    int4 q = *(const int4*)(epack + e + half * 2);  // 2 edges per half-wave
    unsigned int u0 = base[(size_t)q.x * 32];
    unsigned int u1 = base[(size_t)q.z * 32];
    float v0 = __int_as_float(q.y), v1 = __int_as_float(q.w);
    a0 += v0 * bflo(u0); a1 += v0 * bfhi(u0);
    a0 += v1 * bflo(u1); a1 += v1 * bfhi(u1);
  }
  if (e + 1 < eend) {  // pair: half0 -> e, half1 -> e+1
    int2 m = epack[e + half];
    float v = __int_as_float(m.y);
    unsigned int u = base[(size_t)m.x * 32];
    a0 += v * bflo(u); a1 += v * bfhi(u);
    e += 2;
  }
  if (e < eend && half == 0) {  // last single
    int2 m = epack[e];
    float v = __int_as_float(m.y);
    unsigned int u = base[(size_t)m.x * 32];
    a0 += v * bflo(u); a1 += v * bfhi(u);
  }
  a0 += __shfl_down(a0, 32, 64);
  a1 += __shfl_down(a1, 32, 64);
  if (lane < 20) {
    float2 o;
    o.x = a0 + b2[2 * lane];
    o.y = a1 + b2[2 * lane + 1];
    *(float2*)(out2 + (size_t)r * 40 + 2 * lane) = o;
  }
}

// ---------------- launch ----------------
extern "C" void kernel_launch(void* const* d_in, const int* in_sizes, int n_in,
                              void* d_out, int out_size, void* d_ws, size_t ws_size,
                              hipStream_t stream) {
  const float* x        = (const float*)d_in[0];
  const int*   edge_row = (const int*)d_in[1];
  const int*   edge_col = (const int*)d_in[2];
  const float* edge_val = (const float*)d_in[3];
  const float* W1       = (const float*)d_in[4];
  const float* b1       = (const float*)d_in[5];
  const float* W2       = (const float*)d_in[6];
  const float* b2       = (const float*)d_in[7];
  const int M = in_sizes[0] / 512;  // 100000 nodes
  const int E = in_sizes[1];        // 3200000 edges

  char* ws = (char*)d_ws;
  size_t off = 0;
  bf16* T1      = (bf16*)(ws + off);  off += (size_t)M * 256 * 2;
  bf16* W1T     = (bf16*)(ws + off);  off += 512 * 256 * 2;
  bf16* W2T     = (bf16*)(ws + off);  off += 48 * 256 * 2;
  bf16* T2p     = (bf16*)(ws + off);  off += (size_t)M * 64 * 2;
  int* counts   = (int*)(ws + off);   off += (size_t)M * 4;
  int* rp       = (int*)(ws + off);   off += (size_t)M * 4;
  off = (off + 15) & ~(size_t)15;
  int2* epack   = (int2*)(ws + off);  off += (size_t)E * 8;

  float* mid  = (float*)d_out;
  float* out2 = mid + (size_t)M * 256;

  hipMemsetAsync(counts, 0, (size_t)M * 4, stream);

  conv_w<<<(512 * 256 + 48 * 256 + 255) / 256, 256, 0, stream>>>(W1, W2, W1T, W2T);
  hist_kernel<<<(E / 4 + 255) / 256, 256, 0, stream>>>(edge_row, counts, E);
  scan_kernel<<<1, 1024, 0, stream>>>(counts, rp, M);
  scatter_kernel<<<(E + 255) / 256, 256, 0, stream>>>(edge_row, edge_col, edge_val,
                                                      rp, epack, E);
  gemm1_kernel<<<(M + 127) / 128, 256, 0, stream>>>(x, W1T, T1, M);
  spmm1_kernel<<<(M + 3) / 4, 256, 0, stream>>>(rp, epack, (const unsigned int*)T1,
                                                b1, mid, M, 0);
  spmm1_kernel<<<(M + 3) / 4, 256, 0, stream>>>(rp, epack, (const unsigned int*)T1,
                                                b1, mid, M, 128);
  gemm2_kernel<<<(M + 63) / 64, 256, 0, stream>>>(mid, W2T, T2p, M);
  spmm2_kernel<<<(M + 3) / 4, 256, 0, stream>>>(rp, epack, (const unsigned int*)T2p,
                                                b2, out2, M);
}

// Round 4
// 816.180 us; speedup vs baseline: 1.5040x; 1.5040x over previous
//
#include <hip/hip_runtime.h>

// GCN forward: mid = relu(spmm(A, x@W1) + b1); out = spmm(A, mid@W2) + b2
// N=100000, F=512, H=256, C=40, E=3.2M.
//
// R4 changes vs R3:
//  - CSR build rewritten as two-level radix partition (bucket = row>>8, NB=391):
//      bhist (LDS histogram) -> bscan (1-block scan) -> partA (LDS-count +
//      per-bucket reservation, sequential run writes) -> partB (per-bucket block,
//      LDS row-count/scan/cursors, writes rp ends + final edge list).
//    Replaces hist (3.2M global atomics) + scan + scatter (260us, 8x write amp).
//  - spmm1 reverted to single full-row pass (512B gather/edge, uint2/lane).
//  - gemm1 reverted to BM=64 (known-good R2 config).
//  - epack_b aliases T1 region (used only before gemm1 writes T1).

typedef __bf16 bf16;
typedef __bf16 bf16x8 __attribute__((ext_vector_type(8)));
typedef float floatx4 __attribute__((ext_vector_type(4)));

#define NBMAX 400

__device__ __forceinline__ float bflo(unsigned int u) { return __uint_as_float(u << 16); }
__device__ __forceinline__ float bfhi(unsigned int u) { return __uint_as_float(u & 0xffff0000u); }

// ---------------- weight conversion ----------------
__global__ __launch_bounds__(256) void conv_w(const float* __restrict__ W1,
                                              const float* __restrict__ W2,
                                              bf16* __restrict__ W1T,
                                              bf16* __restrict__ W2T) {
  int i = blockIdx.x * 256 + threadIdx.x;
  if (i < 512 * 256) {             // W1 [512][256] -> W1T [256][512]
    int k = i >> 8, n = i & 255;
    W1T[n * 512 + k] = (bf16)W1[i];
  }
  int j = i - 512 * 256;
  if (j >= 0 && j < 48 * 256) {    // W2 [256][40] -> W2T [48][256], pad rows 40..47
    int n = j >> 8, k = j & 255;
    W2T[j] = (n < 40) ? (bf16)W2[k * 40 + n] : (bf16)0.0f;
  }
}

// ---------------- partition stage 1: bucket histogram ----------------
__global__ __launch_bounds__(256) void bhist_kernel(const int* __restrict__ er,
                                                    int* __restrict__ gbcount,
                                                    int E, int NB) {
  __shared__ int cnt[NBMAX];
  const int t = threadIdx.x;
  for (int b = t; b < NB; b += 256) cnt[b] = 0;
  __syncthreads();
  const int base = blockIdx.x * 8192;
#pragma unroll
  for (int k = 0; k < 8; k++) {
    int i = base + k * 1024 + t * 4;
    if (i < E) {  // E % 4 == 0
      int4 r = *(const int4*)(er + i);
      atomicAdd(&cnt[r.x >> 8], 1);
      atomicAdd(&cnt[r.y >> 8], 1);
      atomicAdd(&cnt[r.z >> 8], 1);
      atomicAdd(&cnt[r.w >> 8], 1);
    }
  }
  __syncthreads();
  for (int b = t; b < NB; b += 256)
    if (cnt[b]) atomicAdd(&gbcount[b], cnt[b]);
}

// ---------------- partition stage 2: bucket scan (1 block, 512 thr) ----------------
__global__ __launch_bounds__(512) void bscan_kernel(const int* __restrict__ gbcount,
                                                    int* __restrict__ bstart,
                                                    int* __restrict__ bcur, int NB) {
  __shared__ int wsum[8];
  const int t = threadIdx.x;
  const int lane = t & 63, wave = t >> 6;
  int v = (t < NB) ? gbcount[t] : 0;
  int incl = v;
#pragma unroll
  for (int d = 1; d < 64; d <<= 1) {
    int o = __shfl_up(incl, d, 64);
    if (lane >= d) incl += o;
  }
  if (lane == 63) wsum[wave] = incl;
  __syncthreads();
  int off = 0;
#pragma unroll
  for (int w = 0; w < 8; w++)
    if (w < wave) off += wsum[w];
  int excl = off + incl - v;
  if (t <= NB) bstart[t] = excl;   // bstart[NB] = E
  if (t < NB) bcur[t] = excl;
}

// ---------------- partition stage 3: scatter into buckets ----------------
// epack_b[i] = ( (row&255)<<17 | col , val )
__global__ __launch_bounds__(256) void partA_kernel(
    const int* __restrict__ er, const int* __restrict__ ec, const float* __restrict__ ev,
    int* __restrict__ bcur, int2* __restrict__ epack_b, int E, int NB) {
  __shared__ int cnt[NBMAX];
  __shared__ int cur[NBMAX];
  const int t = threadIdx.x;
  for (int b = t; b < NB; b += 256) cnt[b] = 0;
  __syncthreads();
  const int base = blockIdx.x * 8192;
#pragma unroll
  for (int k = 0; k < 8; k++) {
    int i = base + k * 1024 + t * 4;
    if (i < E) {
      int4 r = *(const int4*)(er + i);
      atomicAdd(&cnt[r.x >> 8], 1);
      atomicAdd(&cnt[r.y >> 8], 1);
      atomicAdd(&cnt[r.z >> 8], 1);
      atomicAdd(&cnt[r.w >> 8], 1);
    }
  }
  __syncthreads();
  for (int b = t; b < NB; b += 256)
    cur[b] = cnt[b] ? atomicAdd(&bcur[b], cnt[b]) : 0;
  __syncthreads();
#pragma unroll
  for (int k = 0; k < 8; k++) {
    int i = base + k * 1024 + t * 4;
    if (i < E) {
      int4 r = *(const int4*)(er + i);
      int4 c = *(const int4*)(ec + i);
      float4 v = *(const float4*)(ev + i);
      int s0 = atomicAdd(&cur[r.x >> 8], 1);
      epack_b[s0] = make_int2(((r.x & 255) << 17) | c.x, __float_as_int(v.x));
      int s1 = atomicAdd(&cur[r.y >> 8], 1);
      epack_b[s1] = make_int2(((r.y & 255) << 17) | c.y, __float_as_int(v.y));
      int s2 = atomicAdd(&cur[r.z >> 8], 1);
      epack_b[s2] = make_int2(((r.z & 255) << 17) | c.z, __float_as_int(v.z));
      int s3 = atomicAdd(&cur[r.w >> 8], 1);
      epack_b[s3] = make_int2(((r.w & 255) << 17) | c.w, __float_as_int(v.w));
    }
  }
}

// ---------------- partition stage 4: per-bucket CSR finalize ----------------
// one block per bucket; LDS row counts -> scan -> cursors; writes rp ends.
__global__ __launch_bounds__(256) void partB_kernel(
    const int2* __restrict__ epack_b, const int* __restrict__ bstart,
    int2* __restrict__ epack_f, int* __restrict__ rp, int M) {
  __shared__ int rcnt[256];
  __shared__ int rcur[256];
  __shared__ int wsum[4];
  const int b = blockIdx.x, t = threadIdx.x;
  const int s = bstart[b];
  const int e_ = bstart[b + 1];
  rcnt[t] = 0;
  __syncthreads();
  for (int i = s + t; i < e_; i += 256) {
    unsigned int ro = ((unsigned int)epack_b[i].x) >> 17;
    atomicAdd(&rcnt[ro], 1);
  }
  __syncthreads();
  const int lane = t & 63, wave = t >> 6;
  int v = rcnt[t];
  int incl = v;
#pragma unroll
  for (int d = 1; d < 64; d <<= 1) {
    int o = __shfl_up(incl, d, 64);
    if (lane >= d) incl += o;
  }
  if (lane == 63) wsum[wave] = incl;
  __syncthreads();
  int off = 0;
#pragma unroll
  for (int w = 0; w < 4; w++)
    if (w < wave) off += wsum[w];
  rcur[t] = s + off + incl - v;  // global exclusive prefix (row start)
  __syncthreads();
  for (int i = s + t; i < e_; i += 256) {
    int2 m = epack_b[i];
    unsigned int ro = ((unsigned int)m.x) >> 17;
    int slot = atomicAdd(&rcur[ro], 1);
    epack_f[slot] = make_int2(m.x & 0x1FFFF, m.y);
  }
  __syncthreads();
  int r = (b << 8) + t;
  if (r < M) rp[r] = rcur[t];  // end of row r
}

// ---------------- GEMM1: T1 = bf16(x @ W1), [M][256], BM=64 ----------------
__global__ __launch_bounds__(256) void gemm1_kernel(const float* __restrict__ x,
                                                    const bf16* __restrict__ W1T,
                                                    bf16* __restrict__ T1, int M) {
  __shared__ __align__(16) bf16 As[64][40];
  __shared__ __align__(16) bf16 Bs[256][40];
  const int t = threadIdx.x;
  const int wave = t >> 6, lane = t & 63;
  const int quad = lane >> 4, l16 = lane & 15;
  const int m0 = blockIdx.x * 64;
  floatx4 acc[16] = {};

  const int ar = t >> 2, aq = t & 3;
  const int a_gr = m0 + ar;
  const float* a_src = x + (size_t)a_gr * 512 + aq * 8;
  const bf16* b_src = W1T + (size_t)t * 512;

  for (int k0 = 0; k0 < 512; k0 += 32) {
    __syncthreads();
    {
      float4 f0 = {0,0,0,0}, f1 = {0,0,0,0};
      if (a_gr < M) {
        const float4* p = (const float4*)(a_src + k0);
        f0 = p[0]; f1 = p[1];
      }
      bf16x8 av;
      av[0] = (bf16)f0.x; av[1] = (bf16)f0.y; av[2] = (bf16)f0.z; av[3] = (bf16)f0.w;
      av[4] = (bf16)f1.x; av[5] = (bf16)f1.y; av[6] = (bf16)f1.z; av[7] = (bf16)f1.w;
      *(bf16x8*)&As[ar][aq * 8] = av;
    }
    {
      const bf16* p = b_src + k0;
      bf16x8 q0 = *(const bf16x8*)(p);
      bf16x8 q1 = *(const bf16x8*)(p + 8);
      bf16x8 q2 = *(const bf16x8*)(p + 16);
      bf16x8 q3 = *(const bf16x8*)(p + 24);
      *(bf16x8*)&Bs[t][0]  = q0;
      *(bf16x8*)&Bs[t][8]  = q1;
      *(bf16x8*)&Bs[t][16] = q2;
      *(bf16x8*)&Bs[t][24] = q3;
    }
    __syncthreads();
    bf16x8 a = *(const bf16x8*)&As[wave * 16 + l16][quad * 8];
#pragma unroll
    for (int nt = 0; nt < 16; nt++) {
      bf16x8 b = *(const bf16x8*)&Bs[nt * 16 + l16][quad * 8];
      acc[nt] = __builtin_amdgcn_mfma_f32_16x16x32_bf16(a, b, acc[nt], 0, 0, 0);
    }
  }
  const int row_base = m0 + wave * 16 + quad * 4;
#pragma unroll
  for (int nt = 0; nt < 16; nt++) {
#pragma unroll
    for (int j = 0; j < 4; j++) {
      int gr = row_base + j;
      if (gr < M) T1[(size_t)gr * 256 + nt * 16 + l16] = (bf16)acc[nt][j];
    }
  }
}

// ---------------- SpMM1: mid = relu(gather-sum(T1) + b1), full 512B rows ----------------
__global__ __launch_bounds__(256) void spmm1_kernel(
    const int* __restrict__ rp, const int2* __restrict__ epack,
    const unsigned int* __restrict__ T1u, const float* __restrict__ b1,
    float* __restrict__ mid, int M) {
  const int lane = threadIdx.x & 63;
  const int r = blockIdx.x * 4 + (threadIdx.x >> 6);
  if (r >= M) return;
  const int eend = rp[r];
  int e = (r == 0) ? 0 : rp[r - 1];
  float a0 = 0.f, a1 = 0.f, a2 = 0.f, a3 = 0.f;
  const unsigned int* base = T1u + lane * 2;  // uint2 per lane, row stride 128 uints
  if (e < eend && (e & 1)) {  // align to even for int4 loads
    int2 m = epack[e];
    float v = __int_as_float(m.y);
    uint2 u = *(const uint2*)(base + (size_t)m.x * 128);
    a0 += v * bflo(u.x); a1 += v * bfhi(u.x); a2 += v * bflo(u.y); a3 += v * bfhi(u.y);
    e++;
  }
  for (; e + 3 < eend; e += 4) {
    int4 p01 = *(const int4*)(epack + e);
    int4 p23 = *(const int4*)(epack + e + 2);
    uint2 u0 = *(const uint2*)(base + (size_t)p01.x * 128);
    uint2 u1 = *(const uint2*)(base + (size_t)p01.z * 128);
    uint2 u2 = *(const uint2*)(base + (size_t)p23.x * 128);
    uint2 u3 = *(const uint2*)(base + (size_t)p23.z * 128);
    float v0 = __int_as_float(p01.y), v1 = __int_as_float(p01.w);
    float v2 = __int_as_float(p23.y), v3 = __int_as_float(p23.w);
    a0 += v0 * bflo(u0.x); a1 += v0 * bfhi(u0.x); a2 += v0 * bflo(u0.y); a3 += v0 * bfhi(u0.y);
    a0 += v1 * bflo(u1.x); a1 += v1 * bfhi(u1.x); a2 += v1 * bflo(u1.y); a3 += v1 * bfhi(u1.y);
    a0 += v2 * bflo(u2.x); a1 += v2 * bfhi(u2.x); a2 += v2 * bflo(u2.y); a3 += v2 * bfhi(u2.y);
    a0 += v3 * bflo(u3.x); a1 += v3 * bfhi(u3.x); a2 += v3 * bflo(u3.y); a3 += v3 * bfhi(u3.y);
  }
  for (; e < eend; e++) {
    int2 m = epack[e];
    float v = __int_as_float(m.y);
    uint2 u = *(const uint2*)(base + (size_t)m.x * 128);
    a0 += v * bflo(u.x); a1 += v * bfhi(u.x); a2 += v * bflo(u.y); a3 += v * bfhi(u.y);
  }
  int c = lane * 4;
  float4 bb = *(const float4*)(b1 + c);
  float4 o;
  o.x = fmaxf(a0 + bb.x, 0.f);
  o.y = fmaxf(a1 + bb.y, 0.f);
  o.z = fmaxf(a2 + bb.z, 0.f);
  o.w = fmaxf(a3 + bb.w, 0.f);
  *(float4*)(mid + (size_t)r * 256 + c) = o;
}

// ---------------- GEMM2: T2p = bf16(mid @ W2), [M][64] (cols 0..39 valid) ----------------
__global__ __launch_bounds__(256) void gemm2_kernel(const float* __restrict__ mid,
                                                    const bf16* __restrict__ W2T,
                                                    bf16* __restrict__ T2p, int M) {
  __shared__ __align__(16) bf16 As[64][40];
  __shared__ __align__(16) bf16 Bs[48][40];
  const int t = threadIdx.x;
  const int wave = t >> 6, lane = t & 63;
  const int quad = lane >> 4, l16 = lane & 15;
  const int m0 = blockIdx.x * 64;
  floatx4 acc[3] = {};
  const int ar = t >> 2, aq = t & 3;
  const int a_gr = m0 + ar;
  const float* a_src = mid + (size_t)a_gr * 256 + aq * 8;

  for (int k0 = 0; k0 < 256; k0 += 32) {
    __syncthreads();
    {
      float4 f0 = {0,0,0,0}, f1 = {0,0,0,0};
      if (a_gr < M) {
        const float4* p = (const float4*)(a_src + k0);
        f0 = p[0]; f1 = p[1];
      }
      bf16x8 av;
      av[0] = (bf16)f0.x; av[1] = (bf16)f0.y; av[2] = (bf16)f0.z; av[3] = (bf16)f0.w;
      av[4] = (bf16)f1.x; av[5] = (bf16)f1.y; av[6] = (bf16)f1.z; av[7] = (bf16)f1.w;
      *(bf16x8*)&As[ar][aq * 8] = av;
    }
    if (t < 192) {
      int n = t >> 2, q = t & 3;
      bf16x8 b = *(const bf16x8*)(W2T + n * 256 + k0 + q * 8);
      *(bf16x8*)&Bs[n][q * 8] = b;
    }
    __syncthreads();
    bf16x8 a = *(const bf16x8*)&As[wave * 16 + l16][quad * 8];
#pragma unroll
    for (int nt = 0; nt < 3; nt++) {
      bf16x8 b = *(const bf16x8*)&Bs[nt * 16 + l16][quad * 8];
      acc[nt] = __builtin_amdgcn_mfma_f32_16x16x32_bf16(a, b, acc[nt], 0, 0, 0);
    }
  }
  const int row_base = m0 + wave * 16 + quad * 4;
#pragma unroll
  for (int nt = 0; nt < 3; nt++) {
#pragma unroll
    for (int j = 0; j < 4; j++) {
      int gr = row_base + j;
      int col = nt * 16 + l16;
      if (gr < M && col < 40) T2p[(size_t)gr * 64 + col] = (bf16)acc[nt][j];
    }
  }
}

// ---------------- SpMM2: out = gather-sum(T2p) + b2 ----------------
__global__ __launch_bounds__(256) void spmm2_kernel(
    const int* __restrict__ rp, const int2* __restrict__ epack,
    const unsigned int* __restrict__ T2u,  // bf16 rows, stride 32 uints (128B)
    const float* __restrict__ b2, float* __restrict__ out2, int M) {
  const int lane = threadIdx.x & 63;
  const int r = blockIdx.x * 4 + (threadIdx.x >> 6);
  if (r >= M) return;
  const int l31 = lane & 31;
  const int half = lane >> 5;
  const int eend = rp[r];
  int e = (r == 0) ? 0 : rp[r - 1];
  float a0 = 0.f, a1 = 0.f;
  const unsigned int* base = T2u + l31;
  if (e < eend && (e & 1)) {  // align; half0 only
    if (half == 0) {
      int2 m = epack[e];
      float v = __int_as_float(m.y);
      unsigned int u = base[(size_t)m.x * 32];
      a0 += v * bflo(u); a1 += v * bfhi(u);
    }
    e++;
  }
  for (; e + 3 < eend; e += 4) {
    int4 q = *(const int4*)(epack + e + half * 2);
    unsigned int u0 = base[(size_t)q.x * 32];
    unsigned int u1 = base[(size_t)q.z * 32];
    float v0 = __int_as_float(q.y), v1 = __int_as_float(q.w);
    a0 += v0 * bflo(u0); a1 += v0 * bfhi(u0);
    a0 += v1 * bflo(u1); a1 += v1 * bfhi(u1);
  }
  if (e + 1 < eend) {
    int2 m = epack[e + half];
    float v = __int_as_float(m.y);
    unsigned int u = base[(size_t)m.x * 32];
    a0 += v * bflo(u); a1 += v * bfhi(u);
    e += 2;
  }
  if (e < eend && half == 0) {
    int2 m = epack[e];
    float v = __int_as_float(m.y);
    unsigned int u = base[(size_t)m.x * 32];
    a0 += v * bflo(u); a1 += v * bfhi(u);
  }
  a0 += __shfl_down(a0, 32, 64);
  a1 += __shfl_down(a1, 32, 64);
  if (lane < 20) {
    float2 o;
    o.x = a0 + b2[2 * lane];
    o.y = a1 + b2[2 * lane + 1];
    *(float2*)(out2 + (size_t)r * 40 + 2 * lane) = o;
  }
}

// ---------------- launch ----------------
extern "C" void kernel_launch(void* const* d_in, const int* in_sizes, int n_in,
                              void* d_out, int out_size, void* d_ws, size_t ws_size,
                              hipStream_t stream) {
  const float* x        = (const float*)d_in[0];
  const int*   edge_row = (const int*)d_in[1];
  const int*   edge_col = (const int*)d_in[2];
  const float* edge_val = (const float*)d_in[3];
  const float* W1       = (const float*)d_in[4];
  const float* b1       = (const float*)d_in[5];
  const float* W2       = (const float*)d_in[6];
  const float* b2       = (const float*)d_in[7];
  const int M = in_sizes[0] / 512;  // 100000 nodes
  const int E = in_sizes[1];        // 3200000 edges
  const int NB = (M + 255) >> 8;    // 391 buckets

  char* ws = (char*)d_ws;
  size_t off = 0;
  bf16* T1      = (bf16*)(ws + off);  off += (size_t)M * 256 * 2;
  bf16* W1T     = (bf16*)(ws + off);  off += 512 * 256 * 2;
  bf16* W2T     = (bf16*)(ws + off);  off += 48 * 256 * 2;
  bf16* T2p     = (bf16*)(ws + off);  off += (size_t)M * 64 * 2;
  int* rp       = (int*)(ws + off);   off += (size_t)M * 4;
  int* gbcount  = (int*)(ws + off);   off += NBMAX * 4;
  int* bstart   = (int*)(ws + off);   off += (NBMAX + 1) * 4;
  int* bcur     = (int*)(ws + off);   off += NBMAX * 4;
  off = (off + 15) & ~(size_t)15;
  int2* epack_f = (int2*)(ws + off);  off += (size_t)E * 8;
  int2* epack_b = (int2*)T1;          // alias: used only before gemm1 writes T1

  float* mid  = (float*)d_out;
  float* out2 = mid + (size_t)M * 256;

  const int EBLK = (E + 8191) / 8192;

  hipMemsetAsync(gbcount, 0, NBMAX * 4, stream);
  conv_w<<<(512 * 256 + 48 * 256 + 255) / 256, 256, 0, stream>>>(W1, W2, W1T, W2T);
  bhist_kernel<<<EBLK, 256, 0, stream>>>(edge_row, gbcount, E, NB);
  bscan_kernel<<<1, 512, 0, stream>>>(gbcount, bstart, bcur, NB);
  partA_kernel<<<EBLK, 256, 0, stream>>>(edge_row, edge_col, edge_val,
                                         bcur, epack_b, E, NB);
  partB_kernel<<<NB, 256, 0, stream>>>(epack_b, bstart, epack_f, rp, M);
  gemm1_kernel<<<(M + 63) / 64, 256, 0, stream>>>(x, W1T, T1, M);
  spmm1_kernel<<<(M + 3) / 4, 256, 0, stream>>>(rp, epack_f, (const unsigned int*)T1,
                                                b1, mid, M);
  gemm2_kernel<<<(M + 63) / 64, 256, 0, stream>>>(mid, W2T, T2p, M);
  spmm2_kernel<<<(M + 3) / 4, 256, 0, stream>>>(rp, epack_f, (const unsigned int*)T2p,
                                                b2, out2, M);
}

// Round 5
// 737.646 us; speedup vs baseline: 1.6641x; 1.1065x over previous
//
#include <hip/hip_runtime.h>

// GCN forward: mid = relu(spmm(A, x@W1) + b1); out = spmm(A, mid@W2) + b2
// N=100000, F=512, H=256, C=40, E=3.2M.
//
// R5 changes vs R4:
//  - spmm gather tables quantized to fp8 e4m3 (OCP, HW cvt):
//      T1f8 [M][256] fp8 (256 B/row)  -> spmm1 gathers 256 B/edge (was 512)
//      T2f8 [M][64]  fp8 (64 B/row)   -> spmm2 gathers one 64-B line/edge (was 128)
//    cvt_fp8_kernel converts bf16->fp8 (8 elems/thread, HW cvt_pk_fp8_f32).
//  - spmm2: quarter-wave (16 lanes) per edge, 4 edges/wave-iter, shfl-tree combine.
//  - partition pipeline (bhist/bscan/partA/partB) unchanged (R4 win).

typedef __bf16 bf16;
typedef __bf16 bf16x8 __attribute__((ext_vector_type(8)));
typedef float floatx4 __attribute__((ext_vector_type(4)));
typedef float floatx2 __attribute__((ext_vector_type(2)));

#define NBMAX 400

__device__ __forceinline__ float bflo(unsigned int u) { return __uint_as_float(u << 16); }
__device__ __forceinline__ float bfhi(unsigned int u) { return __uint_as_float(u & 0xffff0000u); }

// ---------------- weight conversion ----------------
__global__ __launch_bounds__(256) void conv_w(const float* __restrict__ W1,
                                              const float* __restrict__ W2,
                                              bf16* __restrict__ W1T,
                                              bf16* __restrict__ W2T) {
  int i = blockIdx.x * 256 + threadIdx.x;
  if (i < 512 * 256) {             // W1 [512][256] -> W1T [256][512]
    int k = i >> 8, n = i & 255;
    W1T[n * 512 + k] = (bf16)W1[i];
  }
  int j = i - 512 * 256;
  if (j >= 0 && j < 48 * 256) {    // W2 [256][40] -> W2T [48][256], pad rows 40..47
    int n = j >> 8, k = j & 255;
    W2T[j] = (n < 40) ? (bf16)W2[k * 40 + n] : (bf16)0.0f;
  }
}

// ---------------- bf16 -> fp8 e4m3 convert (8 elems / thread) ----------------
__global__ __launch_bounds__(256) void cvt_fp8_kernel(const unsigned int* __restrict__ in,
                                                      unsigned int* __restrict__ out,
                                                      int n8) {
  int i = blockIdx.x * 256 + threadIdx.x;
  if (i >= n8) return;
  uint4 u = ((const uint4*)in)[i];
  int p0 = 0, p1 = 0;
  p0 = __builtin_amdgcn_cvt_pk_fp8_f32(bflo(u.x), bfhi(u.x), p0, false);
  p0 = __builtin_amdgcn_cvt_pk_fp8_f32(bflo(u.y), bfhi(u.y), p0, true);
  p1 = __builtin_amdgcn_cvt_pk_fp8_f32(bflo(u.z), bfhi(u.z), p1, false);
  p1 = __builtin_amdgcn_cvt_pk_fp8_f32(bflo(u.w), bfhi(u.w), p1, true);
  ((uint2*)out)[i] = make_uint2((unsigned int)p0, (unsigned int)p1);
}

// ---------------- partition stage 1: bucket histogram ----------------
__global__ __launch_bounds__(256) void bhist_kernel(const int* __restrict__ er,
                                                    int* __restrict__ gbcount,
                                                    int E, int NB) {
  __shared__ int cnt[NBMAX];
  const int t = threadIdx.x;
  for (int b = t; b < NB; b += 256) cnt[b] = 0;
  __syncthreads();
  const int base = blockIdx.x * 8192;
#pragma unroll
  for (int k = 0; k < 8; k++) {
    int i = base + k * 1024 + t * 4;
    if (i < E) {  // E % 4 == 0
      int4 r = *(const int4*)(er + i);
      atomicAdd(&cnt[r.x >> 8], 1);
      atomicAdd(&cnt[r.y >> 8], 1);
      atomicAdd(&cnt[r.z >> 8], 1);
      atomicAdd(&cnt[r.w >> 8], 1);
    }
  }
  __syncthreads();
  for (int b = t; b < NB; b += 256)
    if (cnt[b]) atomicAdd(&gbcount[b], cnt[b]);
}

// ---------------- partition stage 2: bucket scan (1 block, 512 thr) ----------------
__global__ __launch_bounds__(512) void bscan_kernel(const int* __restrict__ gbcount,
                                                    int* __restrict__ bstart,
                                                    int* __restrict__ bcur, int NB) {
  __shared__ int wsum[8];
  const int t = threadIdx.x;
  const int lane = t & 63, wave = t >> 6;
  int v = (t < NB) ? gbcount[t] : 0;
  int incl = v;
#pragma unroll
  for (int d = 1; d < 64; d <<= 1) {
    int o = __shfl_up(incl, d, 64);
    if (lane >= d) incl += o;
  }
  if (lane == 63) wsum[wave] = incl;
  __syncthreads();
  int off = 0;
#pragma unroll
  for (int w = 0; w < 8; w++)
    if (w < wave) off += wsum[w];
  int excl = off + incl - v;
  if (t <= NB) bstart[t] = excl;   // bstart[NB] = E
  if (t < NB) bcur[t] = excl;
}

// ---------------- partition stage 3: scatter into buckets ----------------
// epack_b[i] = ( (row&255)<<17 | col , val )
__global__ __launch_bounds__(256) void partA_kernel(
    const int* __restrict__ er, const int* __restrict__ ec, const float* __restrict__ ev,
    int* __restrict__ bcur, int2* __restrict__ epack_b, int E, int NB) {
  __shared__ int cnt[NBMAX];
  __shared__ int cur[NBMAX];
  const int t = threadIdx.x;
  for (int b = t; b < NB; b += 256) cnt[b] = 0;
  __syncthreads();
  const int base = blockIdx.x * 8192;
#pragma unroll
  for (int k = 0; k < 8; k++) {
    int i = base + k * 1024 + t * 4;
    if (i < E) {
      int4 r = *(const int4*)(er + i);
      atomicAdd(&cnt[r.x >> 8], 1);
      atomicAdd(&cnt[r.y >> 8], 1);
      atomicAdd(&cnt[r.z >> 8], 1);
      atomicAdd(&cnt[r.w >> 8], 1);
    }
  }
  __syncthreads();
  for (int b = t; b < NB; b += 256)
    cur[b] = cnt[b] ? atomicAdd(&bcur[b], cnt[b]) : 0;
  __syncthreads();
#pragma unroll
  for (int k = 0; k < 8; k++) {
    int i = base + k * 1024 + t * 4;
    if (i < E) {
      int4 r = *(const int4*)(er + i);
      int4 c = *(const int4*)(ec + i);
      float4 v = *(const float4*)(ev + i);
      int s0 = atomicAdd(&cur[r.x >> 8], 1);
      epack_b[s0] = make_int2(((r.x & 255) << 17) | c.x, __float_as_int(v.x));
      int s1 = atomicAdd(&cur[r.y >> 8], 1);
      epack_b[s1] = make_int2(((r.y & 255) << 17) | c.y, __float_as_int(v.y));
      int s2 = atomicAdd(&cur[r.z >> 8], 1);
      epack_b[s2] = make_int2(((r.z & 255) << 17) | c.z, __float_as_int(v.z));
      int s3 = atomicAdd(&cur[r.w >> 8], 1);
      epack_b[s3] = make_int2(((r.w & 255) << 17) | c.w, __float_as_int(v.w));
    }
  }
}

// ---------------- partition stage 4: per-bucket CSR finalize ----------------
__global__ __launch_bounds__(256) void partB_kernel(
    const int2* __restrict__ epack_b, const int* __restrict__ bstart,
    int2* __restrict__ epack_f, int* __restrict__ rp, int M) {
  __shared__ int rcnt[256];
  __shared__ int rcur[256];
  __shared__ int wsum[4];
  const int b = blockIdx.x, t = threadIdx.x;
  const int s = bstart[b];
  const int e_ = bstart[b + 1];
  rcnt[t] = 0;
  __syncthreads();
  for (int i = s + t; i < e_; i += 256) {
    unsigned int ro = ((unsigned int)epack_b[i].x) >> 17;
    atomicAdd(&rcnt[ro], 1);
  }
  __syncthreads();
  const int lane = t & 63, wave = t >> 6;
  int v = rcnt[t];
  int incl = v;
#pragma unroll
  for (int d = 1; d < 64; d <<= 1) {
    int o = __shfl_up(incl, d, 64);
    if (lane >= d) incl += o;
  }
  if (lane == 63) wsum[wave] = incl;
  __syncthreads();
  int off = 0;
#pragma unroll
  for (int w = 0; w < 4; w++)
    if (w < wave) off += wsum[w];
  rcur[t] = s + off + incl - v;
  __syncthreads();
  for (int i = s + t; i < e_; i += 256) {
    int2 m = epack_b[i];
    unsigned int ro = ((unsigned int)m.x) >> 17;
    int slot = atomicAdd(&rcur[ro], 1);
    epack_f[slot] = make_int2(m.x & 0x1FFFF, m.y);
  }
  __syncthreads();
  int r = (b << 8) + t;
  if (r < M) rp[r] = rcur[t];  // end of row r
}

// ---------------- GEMM1: T1 = bf16(x @ W1), [M][256], BM=64 ----------------
__global__ __launch_bounds__(256) void gemm1_kernel(const float* __restrict__ x,
                                                    const bf16* __restrict__ W1T,
                                                    bf16* __restrict__ T1, int M) {
  __shared__ __align__(16) bf16 As[64][40];
  __shared__ __align__(16) bf16 Bs[256][40];
  const int t = threadIdx.x;
  const int wave = t >> 6, lane = t & 63;
  const int quad = lane >> 4, l16 = lane & 15;
  const int m0 = blockIdx.x * 64;
  floatx4 acc[16] = {};

  const int ar = t >> 2, aq = t & 3;
  const int a_gr = m0 + ar;
  const float* a_src = x + (size_t)a_gr * 512 + aq * 8;
  const bf16* b_src = W1T + (size_t)t * 512;

  for (int k0 = 0; k0 < 512; k0 += 32) {
    __syncthreads();
    {
      float4 f0 = {0,0,0,0}, f1 = {0,0,0,0};
      if (a_gr < M) {
        const float4* p = (const float4*)(a_src + k0);
        f0 = p[0]; f1 = p[1];
      }
      bf16x8 av;
      av[0] = (bf16)f0.x; av[1] = (bf16)f0.y; av[2] = (bf16)f0.z; av[3] = (bf16)f0.w;
      av[4] = (bf16)f1.x; av[5] = (bf16)f1.y; av[6] = (bf16)f1.z; av[7] = (bf16)f1.w;
      *(bf16x8*)&As[ar][aq * 8] = av;
    }
    {
      const bf16* p = b_src + k0;
      bf16x8 q0 = *(const bf16x8*)(p);
      bf16x8 q1 = *(const bf16x8*)(p + 8);
      bf16x8 q2 = *(const bf16x8*)(p + 16);
      bf16x8 q3 = *(const bf16x8*)(p + 24);
      *(bf16x8*)&Bs[t][0]  = q0;
      *(bf16x8*)&Bs[t][8]  = q1;
      *(bf16x8*)&Bs[t][16] = q2;
      *(bf16x8*)&Bs[t][24] = q3;
    }
    __syncthreads();
    bf16x8 a = *(const bf16x8*)&As[wave * 16 + l16][quad * 8];
#pragma unroll
    for (int nt = 0; nt < 16; nt++) {
      bf16x8 b = *(const bf16x8*)&Bs[nt * 16 + l16][quad * 8];
      acc[nt] = __builtin_amdgcn_mfma_f32_16x16x32_bf16(a, b, acc[nt], 0, 0, 0);
    }
  }
  const int row_base = m0 + wave * 16 + quad * 4;
#pragma unroll
  for (int nt = 0; nt < 16; nt++) {
#pragma unroll
    for (int j = 0; j < 4; j++) {
      int gr = row_base + j;
      if (gr < M) T1[(size_t)gr * 256 + nt * 16 + l16] = (bf16)acc[nt][j];
    }
  }
}

// ---------------- SpMM1: mid = relu(gather-sum(T1f8) + b1) ----------------
// lane covers features 4*lane..4*lane+3; row = 64 uints (256 fp8).
__global__ __launch_bounds__(256) void spmm1_kernel(
    const int* __restrict__ rp, const int2* __restrict__ epack,
    const unsigned int* __restrict__ T1f8, const float* __restrict__ b1,
    float* __restrict__ mid, int M) {
  const int lane = threadIdx.x & 63;
  const int r = blockIdx.x * 4 + (threadIdx.x >> 6);
  if (r >= M) return;
  const int eend = rp[r];
  int e = (r == 0) ? 0 : rp[r - 1];
  float a0 = 0.f, a1 = 0.f, a2 = 0.f, a3 = 0.f;
  const unsigned int* base = T1f8 + lane;  // 4 fp8 per lane, row stride 64 uints
  if (e < eend && (e & 1)) {  // align to even for int4 loads
    int2 m = epack[e];
    float v = __int_as_float(m.y);
    unsigned int u = base[(size_t)m.x * 64];
    floatx2 lo = __builtin_amdgcn_cvt_pk_f32_fp8(u, false);
    floatx2 hi = __builtin_amdgcn_cvt_pk_f32_fp8(u, true);
    a0 += v * lo[0]; a1 += v * lo[1]; a2 += v * hi[0]; a3 += v * hi[1];
    e++;
  }
  for (; e + 3 < eend; e += 4) {
    int4 p01 = *(const int4*)(epack + e);
    int4 p23 = *(const int4*)(epack + e + 2);
    unsigned int u0 = base[(size_t)p01.x * 64];
    unsigned int u1 = base[(size_t)p01.z * 64];
    unsigned int u2 = base[(size_t)p23.x * 64];
    unsigned int u3 = base[(size_t)p23.z * 64];
    float v0 = __int_as_float(p01.y), v1 = __int_as_float(p01.w);
    float v2 = __int_as_float(p23.y), v3 = __int_as_float(p23.w);
    floatx2 l0 = __builtin_amdgcn_cvt_pk_f32_fp8(u0, false);
    floatx2 h0 = __builtin_amdgcn_cvt_pk_f32_fp8(u0, true);
    floatx2 l1 = __builtin_amdgcn_cvt_pk_f32_fp8(u1, false);
    floatx2 h1 = __builtin_amdgcn_cvt_pk_f32_fp8(u1, true);
    floatx2 l2 = __builtin_amdgcn_cvt_pk_f32_fp8(u2, false);
    floatx2 h2 = __builtin_amdgcn_cvt_pk_f32_fp8(u2, true);
    floatx2 l3 = __builtin_amdgcn_cvt_pk_f32_fp8(u3, false);
    floatx2 h3 = __builtin_amdgcn_cvt_pk_f32_fp8(u3, true);
    a0 += v0 * l0[0]; a1 += v0 * l0[1]; a2 += v0 * h0[0]; a3 += v0 * h0[1];
    a0 += v1 * l1[0]; a1 += v1 * l1[1]; a2 += v1 * h1[0]; a3 += v1 * h1[1];
    a0 += v2 * l2[0]; a1 += v2 * l2[1]; a2 += v2 * h2[0]; a3 += v2 * h2[1];
    a0 += v3 * l3[0]; a1 += v3 * l3[1]; a2 += v3 * h3[0]; a3 += v3 * h3[1];
  }
  for (; e < eend; e++) {
    int2 m = epack[e];
    float v = __int_as_float(m.y);
    unsigned int u = base[(size_t)m.x * 64];
    floatx2 lo = __builtin_amdgcn_cvt_pk_f32_fp8(u, false);
    floatx2 hi = __builtin_amdgcn_cvt_pk_f32_fp8(u, true);
    a0 += v * lo[0]; a1 += v * lo[1]; a2 += v * hi[0]; a3 += v * hi[1];
  }
  int c = lane * 4;
  float4 bb = *(const float4*)(b1 + c);
  float4 o;
  o.x = fmaxf(a0 + bb.x, 0.f);
  o.y = fmaxf(a1 + bb.y, 0.f);
  o.z = fmaxf(a2 + bb.z, 0.f);
  o.w = fmaxf(a3 + bb.w, 0.f);
  *(float4*)(mid + (size_t)r * 256 + c) = o;
}

// ---------------- GEMM2: T2p = bf16(mid @ W2), [M][64] (cols 0..39 valid) ----------------
__global__ __launch_bounds__(256) void gemm2_kernel(const float* __restrict__ mid,
                                                    const bf16* __restrict__ W2T,
                                                    bf16* __restrict__ T2p, int M) {
  __shared__ __align__(16) bf16 As[64][40];
  __shared__ __align__(16) bf16 Bs[48][40];
  const int t = threadIdx.x;
  const int wave = t >> 6, lane = t & 63;
  const int quad = lane >> 4, l16 = lane & 15;
  const int m0 = blockIdx.x * 64;
  floatx4 acc[3] = {};
  const int ar = t >> 2, aq = t & 3;
  const int a_gr = m0 + ar;
  const float* a_src = mid + (size_t)a_gr * 256 + aq * 8;

  for (int k0 = 0; k0 < 256; k0 += 32) {
    __syncthreads();
    {
      float4 f0 = {0,0,0,0}, f1 = {0,0,0,0};
      if (a_gr < M) {
        const float4* p = (const float4*)(a_src + k0);
        f0 = p[0]; f1 = p[1];
      }
      bf16x8 av;
      av[0] = (bf16)f0.x; av[1] = (bf16)f0.y; av[2] = (bf16)f0.z; av[3] = (bf16)f0.w;
      av[4] = (bf16)f1.x; av[5] = (bf16)f1.y; av[6] = (bf16)f1.z; av[7] = (bf16)f1.w;
      *(bf16x8*)&As[ar][aq * 8] = av;
    }
    if (t < 192) {
      int n = t >> 2, q = t & 3;
      bf16x8 b = *(const bf16x8*)(W2T + n * 256 + k0 + q * 8);
      *(bf16x8*)&Bs[n][q * 8] = b;
    }
    __syncthreads();
    bf16x8 a = *(const bf16x8*)&As[wave * 16 + l16][quad * 8];
#pragma unroll
    for (int nt = 0; nt < 3; nt++) {
      bf16x8 b = *(const bf16x8*)&Bs[nt * 16 + l16][quad * 8];
      acc[nt] = __builtin_amdgcn_mfma_f32_16x16x32_bf16(a, b, acc[nt], 0, 0, 0);
    }
  }
  const int row_base = m0 + wave * 16 + quad * 4;
#pragma unroll
  for (int nt = 0; nt < 3; nt++) {
#pragma unroll
    for (int j = 0; j < 4; j++) {
      int gr = row_base + j;
      int col = nt * 16 + l16;
      if (gr < M && col < 40) T2p[(size_t)gr * 64 + col] = (bf16)acc[nt][j];
    }
  }
}

// ---------------- SpMM2: out = gather-sum(T2f8) + b2 ----------------
// quarter-wave (16 lanes) per edge, 4 edges per wave-iter; lane q covers
// cols 4q..4q+3 (valid q<10); row = 16 uints (64 B line). shfl-tree combine.
__global__ __launch_bounds__(256) void spmm2_kernel(
    const int* __restrict__ rp, const int2* __restrict__ epack,
    const unsigned int* __restrict__ T2f8, const float* __restrict__ b2,
    float* __restrict__ out2, int M) {
  const int lane = threadIdx.x & 63;
  const int r = blockIdx.x * 4 + (threadIdx.x >> 6);
  if (r >= M) return;
  const int q = lane & 15;
  const int g = lane >> 4;  // edge group 0..3
  const int eend = rp[r];
  int e = (r == 0) ? 0 : rp[r - 1];
  float a0 = 0.f, a1 = 0.f, a2 = 0.f, a3 = 0.f;
  const unsigned int* base = T2f8 + q;  // row stride 16 uints
  for (; e + 3 < eend; e += 4) {
    int2 m = epack[e + g];
    float v = __int_as_float(m.y);
    unsigned int u = base[(size_t)m.x * 16];
    floatx2 lo = __builtin_amdgcn_cvt_pk_f32_fp8(u, false);
    floatx2 hi = __builtin_amdgcn_cvt_pk_f32_fp8(u, true);
    a0 += v * lo[0]; a1 += v * lo[1]; a2 += v * hi[0]; a3 += v * hi[1];
  }
  if (e + g < eend) {  // tail: groups 0..(eend-e-1)
    int2 m = epack[e + g];
    float v = __int_as_float(m.y);
    unsigned int u = base[(size_t)m.x * 16];
    floatx2 lo = __builtin_amdgcn_cvt_pk_f32_fp8(u, false);
    floatx2 hi = __builtin_amdgcn_cvt_pk_f32_fp8(u, true);
    a0 += v * lo[0]; a1 += v * lo[1]; a2 += v * hi[0]; a3 += v * hi[1];
  }
  a0 += __shfl_down(a0, 32, 64); a0 += __shfl_down(a0, 16, 64);
  a1 += __shfl_down(a1, 32, 64); a1 += __shfl_down(a1, 16, 64);
  a2 += __shfl_down(a2, 32, 64); a2 += __shfl_down(a2, 16, 64);
  a3 += __shfl_down(a3, 32, 64); a3 += __shfl_down(a3, 16, 64);
  if (lane < 10) {
    int c = lane * 4;
    float4 o;
    o.x = a0 + b2[c];
    o.y = a1 + b2[c + 1];
    o.z = a2 + b2[c + 2];
    o.w = a3 + b2[c + 3];
    *(float4*)(out2 + (size_t)r * 40 + c) = o;
  }
}

// ---------------- launch ----------------
extern "C" void kernel_launch(void* const* d_in, const int* in_sizes, int n_in,
                              void* d_out, int out_size, void* d_ws, size_t ws_size,
                              hipStream_t stream) {
  const float* x        = (const float*)d_in[0];
  const int*   edge_row = (const int*)d_in[1];
  const int*   edge_col = (const int*)d_in[2];
  const float* edge_val = (const float*)d_in[3];
  const float* W1       = (const float*)d_in[4];
  const float* b1       = (const float*)d_in[5];
  const float* W2       = (const float*)d_in[6];
  const float* b2       = (const float*)d_in[7];
  const int M = in_sizes[0] / 512;  // 100000 nodes
  const int E = in_sizes[1];        // 3200000 edges
  const int NB = (M + 255) >> 8;    // 391 buckets

  char* ws = (char*)d_ws;
  size_t off = 0;
  bf16* T1      = (bf16*)(ws + off);  off += (size_t)M * 256 * 2;
  bf16* W1T     = (bf16*)(ws + off);  off += 512 * 256 * 2;
  bf16* W2T     = (bf16*)(ws + off);  off += 48 * 256 * 2;
  bf16* T2p     = (bf16*)(ws + off);  off += (size_t)M * 64 * 2;
  unsigned int* T1f8 = (unsigned int*)(ws + off); off += (size_t)M * 256;
  unsigned int* T2f8 = (unsigned int*)(ws + off); off += (size_t)M * 64;
  int* rp       = (int*)(ws + off);   off += (size_t)M * 4;
  int* gbcount  = (int*)(ws + off);   off += NBMAX * 4;
  int* bstart   = (int*)(ws + off);   off += (NBMAX + 1) * 4;
  int* bcur     = (int*)(ws + off);   off += NBMAX * 4;
  off = (off + 15) & ~(size_t)15;
  int2* epack_f = (int2*)(ws + off);  off += (size_t)E * 8;
  int2* epack_b = (int2*)T1;          // alias: used only before gemm1 writes T1

  float* mid  = (float*)d_out;
  float* out2 = mid + (size_t)M * 256;

  const int EBLK = (E + 8191) / 8192;

  hipMemsetAsync(gbcount, 0, NBMAX * 4, stream);
  conv_w<<<(512 * 256 + 48 * 256 + 255) / 256, 256, 0, stream>>>(W1, W2, W1T, W2T);
  bhist_kernel<<<EBLK, 256, 0, stream>>>(edge_row, gbcount, E, NB);
  bscan_kernel<<<1, 512, 0, stream>>>(gbcount, bstart, bcur, NB);
  partA_kernel<<<EBLK, 256, 0, stream>>>(edge_row, edge_col, edge_val,
                                         bcur, epack_b, E, NB);
  partB_kernel<<<NB, 256, 0, stream>>>(epack_b, bstart, epack_f, rp, M);
  gemm1_kernel<<<(M + 63) / 64, 256, 0, stream>>>(x, W1T, T1, M);
  {
    int n8 = M * 256 / 8;
    cvt_fp8_kernel<<<(n8 + 255) / 256, 256, 0, stream>>>((const unsigned int*)T1,
                                                         T1f8, n8);
  }
  spmm1_kernel<<<(M + 3) / 4, 256, 0, stream>>>(rp, epack_f, T1f8, b1, mid, M);
  gemm2_kernel<<<(M + 63) / 64, 256, 0, stream>>>(mid, W2T, T2p, M);
  {
    int n8 = M * 64 / 8;
    cvt_fp8_kernel<<<(n8 + 255) / 256, 256, 0, stream>>>((const unsigned int*)T2p,
                                                         T2f8, n8);
  }
  spmm2_kernel<<<(M + 3) / 4, 256, 0, stream>>>(rp, epack_f, T2f8, b2, out2, M);
}

// Round 6
// 691.407 us; speedup vs baseline: 1.7754x; 1.0669x over previous
//
#include <hip/hip_runtime.h>

// GCN forward: mid = relu(spmm(A, x@W1) + b1); out = spmm(A, mid@W2) + b2
// N=100000, F=512, H=256, C=40, E=3.2M.
//
// R6 changes vs R5:
//  - spmm1/spmm2 unrolled to 8 edges in flight per wave-iter (latency hiding).
//  - partition: bhist persists per-(bucket,block) counts; new bscan2 kernel
//    turns them into per-block write cursors; partA loses its entire counting
//    pass (no er re-read, no 2nd set of 3.2M LDS atomics, no bcur contention).
//  - fp8 e4m3 gather tables unchanged (absmax 3.0/3.26 - margin spent, no
//    further quantization).

typedef __bf16 bf16;
typedef __bf16 bf16x8 __attribute__((ext_vector_type(8)));
typedef float floatx4 __attribute__((ext_vector_type(4)));
typedef float floatx2 __attribute__((ext_vector_type(2)));

#define NBMAX 400

__device__ __forceinline__ float bflo(unsigned int u) { return __uint_as_float(u << 16); }
__device__ __forceinline__ float bfhi(unsigned int u) { return __uint_as_float(u & 0xffff0000u); }

// ---------------- weight conversion ----------------
__global__ __launch_bounds__(256) void conv_w(const float* __restrict__ W1,
                                              const float* __restrict__ W2,
                                              bf16* __restrict__ W1T,
                                              bf16* __restrict__ W2T) {
  int i = blockIdx.x * 256 + threadIdx.x;
  if (i < 512 * 256) {             // W1 [512][256] -> W1T [256][512]
    int k = i >> 8, n = i & 255;
    W1T[n * 512 + k] = (bf16)W1[i];
  }
  int j = i - 512 * 256;
  if (j >= 0 && j < 48 * 256) {    // W2 [256][40] -> W2T [48][256], pad rows 40..47
    int n = j >> 8, k = j & 255;
    W2T[j] = (n < 40) ? (bf16)W2[k * 40 + n] : (bf16)0.0f;
  }
}

// ---------------- bf16 -> fp8 e4m3 convert (8 elems / thread) ----------------
__global__ __launch_bounds__(256) void cvt_fp8_kernel(const unsigned int* __restrict__ in,
                                                      unsigned int* __restrict__ out,
                                                      int n8) {
  int i = blockIdx.x * 256 + threadIdx.x;
  if (i >= n8) return;
  uint4 u = ((const uint4*)in)[i];
  int p0 = 0, p1 = 0;
  p0 = __builtin_amdgcn_cvt_pk_fp8_f32(bflo(u.x), bfhi(u.x), p0, false);
  p0 = __builtin_amdgcn_cvt_pk_fp8_f32(bflo(u.y), bfhi(u.y), p0, true);
  p1 = __builtin_amdgcn_cvt_pk_fp8_f32(bflo(u.z), bfhi(u.z), p1, false);
  p1 = __builtin_amdgcn_cvt_pk_fp8_f32(bflo(u.w), bfhi(u.w), p1, true);
  ((uint2*)out)[i] = make_uint2((unsigned int)p0, (unsigned int)p1);
}

// ---------------- partition stage 1: bucket histogram (persisted per block) ----
__global__ __launch_bounds__(256) void bhist_kernel(const int* __restrict__ er,
                                                    int* __restrict__ gbcount,
                                                    int* __restrict__ blkcnt,
                                                    int E, int NB, int EBLK) {
  __shared__ int cnt[NBMAX];
  const int t = threadIdx.x;
  for (int b = t; b < NB; b += 256) cnt[b] = 0;
  __syncthreads();
  const int base = blockIdx.x * 8192;
#pragma unroll
  for (int k = 0; k < 8; k++) {
    int i = base + k * 1024 + t * 4;
    if (i < E) {  // E % 4 == 0
      int4 r = *(const int4*)(er + i);
      atomicAdd(&cnt[r.x >> 8], 1);
      atomicAdd(&cnt[r.y >> 8], 1);
      atomicAdd(&cnt[r.z >> 8], 1);
      atomicAdd(&cnt[r.w >> 8], 1);
    }
  }
  __syncthreads();
  for (int b = t; b < NB; b += 256) {
    int c = cnt[b];
    blkcnt[b * EBLK + blockIdx.x] = c;
    if (c) atomicAdd(&gbcount[b], c);
  }
}

// ---------------- partition stage 2: bucket scan (1 block, 512 thr) ----------------
__global__ __launch_bounds__(512) void bscan_kernel(const int* __restrict__ gbcount,
                                                    int* __restrict__ bstart, int NB) {
  __shared__ int wsum[8];
  const int t = threadIdx.x;
  const int lane = t & 63, wave = t >> 6;
  int v = (t < NB) ? gbcount[t] : 0;
  int incl = v;
#pragma unroll
  for (int d = 1; d < 64; d <<= 1) {
    int o = __shfl_up(incl, d, 64);
    if (lane >= d) incl += o;
  }
  if (lane == 63) wsum[wave] = incl;
  __syncthreads();
  int off = 0;
#pragma unroll
  for (int w = 0; w < 8; w++)
    if (w < wave) off += wsum[w];
  int excl = off + incl - v;
  if (t <= NB) bstart[t] = excl;   // bstart[NB] = E
}

// ---------------- partition stage 2b: per-bucket cross-block scan ----------------
// block b: blkoff[b*EBLK + j] = bstart[b] + sum(blkcnt[b*EBLK + 0..j-1])
__global__ __launch_bounds__(512) void bscan2_kernel(const int* __restrict__ blkcnt,
                                                     const int* __restrict__ bstart,
                                                     int* __restrict__ blkoff, int EBLK) {
  __shared__ int wsum[8];
  const int b = blockIdx.x, t = threadIdx.x;
  const int lane = t & 63, wave = t >> 6;
  int v = (t < EBLK) ? blkcnt[b * EBLK + t] : 0;
  int incl = v;
#pragma unroll
  for (int d = 1; d < 64; d <<= 1) {
    int o = __shfl_up(incl, d, 64);
    if (lane >= d) incl += o;
  }
  if (lane == 63) wsum[wave] = incl;
  __syncthreads();
  int off = 0;
#pragma unroll
  for (int w = 0; w < 8; w++)
    if (w < wave) off += wsum[w];
  if (t < EBLK) blkoff[b * EBLK + t] = bstart[b] + off + incl - v;
}

// ---------------- partition stage 3: scatter into buckets ----------------
// epack_b[i] = ( (row&255)<<17 | col , val )
__global__ __launch_bounds__(256) void partA_kernel(
    const int* __restrict__ er, const int* __restrict__ ec, const float* __restrict__ ev,
    const int* __restrict__ blkoff, int2* __restrict__ epack_b, int E, int NB, int EBLK) {
  __shared__ int cur[NBMAX];
  const int t = threadIdx.x;
  for (int b = t; b < NB; b += 256) cur[b] = blkoff[b * EBLK + blockIdx.x];
  __syncthreads();
  const int base = blockIdx.x * 8192;
#pragma unroll
  for (int k = 0; k < 8; k++) {
    int i = base + k * 1024 + t * 4;
    if (i < E) {
      int4 r = *(const int4*)(er + i);
      int4 c = *(const int4*)(ec + i);
      float4 v = *(const float4*)(ev + i);
      int s0 = atomicAdd(&cur[r.x >> 8], 1);
      epack_b[s0] = make_int2(((r.x & 255) << 17) | c.x, __float_as_int(v.x));
      int s1 = atomicAdd(&cur[r.y >> 8], 1);
      epack_b[s1] = make_int2(((r.y & 255) << 17) | c.y, __float_as_int(v.y));
      int s2 = atomicAdd(&cur[r.z >> 8], 1);
      epack_b[s2] = make_int2(((r.z & 255) << 17) | c.z, __float_as_int(v.z));
      int s3 = atomicAdd(&cur[r.w >> 8], 1);
      epack_b[s3] = make_int2(((r.w & 255) << 17) | c.w, __float_as_int(v.w));
    }
  }
}

// ---------------- partition stage 4: per-bucket CSR finalize ----------------
__global__ __launch_bounds__(256) void partB_kernel(
    const int2* __restrict__ epack_b, const int* __restrict__ bstart,
    int2* __restrict__ epack_f, int* __restrict__ rp, int M) {
  __shared__ int rcnt[256];
  __shared__ int rcur[256];
  __shared__ int wsum[4];
  const int b = blockIdx.x, t = threadIdx.x;
  const int s = bstart[b];
  const int e_ = bstart[b + 1];
  rcnt[t] = 0;
  __syncthreads();
  for (int i = s + t; i < e_; i += 256) {
    unsigned int ro = ((unsigned int)epack_b[i].x) >> 17;
    atomicAdd(&rcnt[ro], 1);
  }
  __syncthreads();
  const int lane = t & 63, wave = t >> 6;
  int v = rcnt[t];
  int incl = v;
#pragma unroll
  for (int d = 1; d < 64; d <<= 1) {
    int o = __shfl_up(incl, d, 64);
    if (lane >= d) incl += o;
  }
  if (lane == 63) wsum[wave] = incl;
  __syncthreads();
  int off = 0;
#pragma unroll
  for (int w = 0; w < 4; w++)
    if (w < wave) off += wsum[w];
  rcur[t] = s + off + incl - v;
  __syncthreads();
  for (int i = s + t; i < e_; i += 256) {
    int2 m = epack_b[i];
    unsigned int ro = ((unsigned int)m.x) >> 17;
    int slot = atomicAdd(&rcur[ro], 1);
    epack_f[slot] = make_int2(m.x & 0x1FFFF, m.y);
  }
  __syncthreads();
  int r = (b << 8) + t;
  if (r < M) rp[r] = rcur[t];  // end of row r
}

// ---------------- GEMM1: T1 = bf16(x @ W1), [M][256], BM=64 ----------------
__global__ __launch_bounds__(256) void gemm1_kernel(const float* __restrict__ x,
                                                    const bf16* __restrict__ W1T,
                                                    bf16* __restrict__ T1, int M) {
  __shared__ __align__(16) bf16 As[64][40];
  __shared__ __align__(16) bf16 Bs[256][40];
  const int t = threadIdx.x;
  const int wave = t >> 6, lane = t & 63;
  const int quad = lane >> 4, l16 = lane & 15;
  const int m0 = blockIdx.x * 64;
  floatx4 acc[16] = {};

  const int ar = t >> 2, aq = t & 3;
  const int a_gr = m0 + ar;
  const float* a_src = x + (size_t)a_gr * 512 + aq * 8;
  const bf16* b_src = W1T + (size_t)t * 512;

  for (int k0 = 0; k0 < 512; k0 += 32) {
    __syncthreads();
    {
      float4 f0 = {0,0,0,0}, f1 = {0,0,0,0};
      if (a_gr < M) {
        const float4* p = (const float4*)(a_src + k0);
        f0 = p[0]; f1 = p[1];
      }
      bf16x8 av;
      av[0] = (bf16)f0.x; av[1] = (bf16)f0.y; av[2] = (bf16)f0.z; av[3] = (bf16)f0.w;
      av[4] = (bf16)f1.x; av[5] = (bf16)f1.y; av[6] = (bf16)f1.z; av[7] = (bf16)f1.w;
      *(bf16x8*)&As[ar][aq * 8] = av;
    }
    {
      const bf16* p = b_src + k0;
      bf16x8 q0 = *(const bf16x8*)(p);
      bf16x8 q1 = *(const bf16x8*)(p + 8);
      bf16x8 q2 = *(const bf16x8*)(p + 16);
      bf16x8 q3 = *(const bf16x8*)(p + 24);
      *(bf16x8*)&Bs[t][0]  = q0;
      *(bf16x8*)&Bs[t][8]  = q1;
      *(bf16x8*)&Bs[t][16] = q2;
      *(bf16x8*)&Bs[t][24] = q3;
    }
    __syncthreads();
    bf16x8 a = *(const bf16x8*)&As[wave * 16 + l16][quad * 8];
#pragma unroll
    for (int nt = 0; nt < 16; nt++) {
      bf16x8 b = *(const bf16x8*)&Bs[nt * 16 + l16][quad * 8];
      acc[nt] = __builtin_amdgcn_mfma_f32_16x16x32_bf16(a, b, acc[nt], 0, 0, 0);
    }
  }
  const int row_base = m0 + wave * 16 + quad * 4;
#pragma unroll
  for (int nt = 0; nt < 16; nt++) {
#pragma unroll
    for (int j = 0; j < 4; j++) {
      int gr = row_base + j;
      if (gr < M) T1[(size_t)gr * 256 + nt * 16 + l16] = (bf16)acc[nt][j];
    }
  }
}

// ---------------- SpMM1: mid = relu(gather-sum(T1f8) + b1) ----------------
// lane covers features 4*lane..4*lane+3; row = 64 uints (256 fp8).
__global__ __launch_bounds__(256) void spmm1_kernel(
    const int* __restrict__ rp, const int2* __restrict__ epack,
    const unsigned int* __restrict__ T1f8, const float* __restrict__ b1,
    float* __restrict__ mid, int M) {
  const int lane = threadIdx.x & 63;
  const int r = blockIdx.x * 4 + (threadIdx.x >> 6);
  if (r >= M) return;
  const int eend = rp[r];
  int e = (r == 0) ? 0 : rp[r - 1];
  float a0 = 0.f, a1 = 0.f, a2 = 0.f, a3 = 0.f;
  const unsigned int* base = T1f8 + lane;  // 4 fp8 per lane, row stride 64 uints
  if (e < eend && (e & 1)) {  // align to even for int4 loads
    int2 m = epack[e];
    float v = __int_as_float(m.y);
    unsigned int u = base[(size_t)m.x * 64];
    floatx2 lo = __builtin_amdgcn_cvt_pk_f32_fp8(u, false);
    floatx2 hi = __builtin_amdgcn_cvt_pk_f32_fp8(u, true);
    a0 += v * lo[0]; a1 += v * lo[1]; a2 += v * hi[0]; a3 += v * hi[1];
    e++;
  }
  for (; e + 7 < eend; e += 8) {
    int4 p01 = *(const int4*)(epack + e);
    int4 p23 = *(const int4*)(epack + e + 2);
    int4 p45 = *(const int4*)(epack + e + 4);
    int4 p67 = *(const int4*)(epack + e + 6);
    unsigned int u0 = base[(size_t)p01.x * 64];
    unsigned int u1 = base[(size_t)p01.z * 64];
    unsigned int u2 = base[(size_t)p23.x * 64];
    unsigned int u3 = base[(size_t)p23.z * 64];
    unsigned int u4 = base[(size_t)p45.x * 64];
    unsigned int u5 = base[(size_t)p45.z * 64];
    unsigned int u6 = base[(size_t)p67.x * 64];
    unsigned int u7 = base[(size_t)p67.z * 64];
    float v0 = __int_as_float(p01.y), v1 = __int_as_float(p01.w);
    float v2 = __int_as_float(p23.y), v3 = __int_as_float(p23.w);
    float v4 = __int_as_float(p45.y), v5 = __int_as_float(p45.w);
    float v6 = __int_as_float(p67.y), v7 = __int_as_float(p67.w);
    floatx2 l0 = __builtin_amdgcn_cvt_pk_f32_fp8(u0, false);
    floatx2 h0 = __builtin_amdgcn_cvt_pk_f32_fp8(u0, true);
    floatx2 l1 = __builtin_amdgcn_cvt_pk_f32_fp8(u1, false);
    floatx2 h1 = __builtin_amdgcn_cvt_pk_f32_fp8(u1, true);
    floatx2 l2 = __builtin_amdgcn_cvt_pk_f32_fp8(u2, false);
    floatx2 h2 = __builtin_amdgcn_cvt_pk_f32_fp8(u2, true);
    floatx2 l3 = __builtin_amdgcn_cvt_pk_f32_fp8(u3, false);
    floatx2 h3 = __builtin_amdgcn_cvt_pk_f32_fp8(u3, true);
    floatx2 l4 = __builtin_amdgcn_cvt_pk_f32_fp8(u4, false);
    floatx2 h4 = __builtin_amdgcn_cvt_pk_f32_fp8(u4, true);
    floatx2 l5 = __builtin_amdgcn_cvt_pk_f32_fp8(u5, false);
    floatx2 h5 = __builtin_amdgcn_cvt_pk_f32_fp8(u5, true);
    floatx2 l6 = __builtin_amdgcn_cvt_pk_f32_fp8(u6, false);
    floatx2 h6 = __builtin_amdgcn_cvt_pk_f32_fp8(u6, true);
    floatx2 l7 = __builtin_amdgcn_cvt_pk_f32_fp8(u7, false);
    floatx2 h7 = __builtin_amdgcn_cvt_pk_f32_fp8(u7, true);
    a0 += v0 * l0[0]; a1 += v0 * l0[1]; a2 += v0 * h0[0]; a3 += v0 * h0[1];
    a0 += v1 * l1[0]; a1 += v1 * l1[1]; a2 += v1 * h1[0]; a3 += v1 * h1[1];
    a0 += v2 * l2[0]; a1 += v2 * l2[1]; a2 += v2 * h2[0]; a3 += v2 * h2[1];
    a0 += v3 * l3[0]; a1 += v3 * l3[1]; a2 += v3 * h3[0]; a3 += v3 * h3[1];
    a0 += v4 * l4[0]; a1 += v4 * l4[1]; a2 += v4 * h4[0]; a3 += v4 * h4[1];
    a0 += v5 * l5[0]; a1 += v5 * l5[1]; a2 += v5 * h5[0]; a3 += v5 * h5[1];
    a0 += v6 * l6[0]; a1 += v6 * l6[1]; a2 += v6 * h6[0]; a3 += v6 * h6[1];
    a0 += v7 * l7[0]; a1 += v7 * l7[1]; a2 += v7 * h7[0]; a3 += v7 * h7[1];
  }
  for (; e + 3 < eend; e += 4) {
    int4 p01 = *(const int4*)(epack + e);
    int4 p23 = *(const int4*)(epack + e + 2);
    unsigned int u0 = base[(size_t)p01.x * 64];
    unsigned int u1 = base[(size_t)p01.z * 64];
    unsigned int u2 = base[(size_t)p23.x * 64];
    unsigned int u3 = base[(size_t)p23.z * 64];
    float v0 = __int_as_float(p01.y), v1 = __int_as_float(p01.w);
    float v2 = __int_as_float(p23.y), v3 = __int_as_float(p23.w);
    floatx2 l0 = __builtin_amdgcn_cvt_pk_f32_fp8(u0, false);
    floatx2 h0 = __builtin_amdgcn_cvt_pk_f32_fp8(u0, true);
    floatx2 l1 = __builtin_amdgcn_cvt_pk_f32_fp8(u1, false);
    floatx2 h1 = __builtin_amdgcn_cvt_pk_f32_fp8(u1, true);
    floatx2 l2 = __builtin_amdgcn_cvt_pk_f32_fp8(u2, false);
    floatx2 h2 = __builtin_amdgcn_cvt_pk_f32_fp8(u2, true);
    floatx2 l3 = __builtin_amdgcn_cvt_pk_f32_fp8(u3, false);
    floatx2 h3 = __builtin_amdgcn_cvt_pk_f32_fp8(u3, true);
    a0 += v0 * l0[0]; a1 += v0 * l0[1]; a2 += v0 * h0[0]; a3 += v0 * h0[1];
    a0 += v1 * l1[0]; a1 += v1 * l1[1]; a2 += v1 * h1[0]; a3 += v1 * h1[1];
    a0 += v2 * l2[0]; a1 += v2 * l2[1]; a2 += v2 * h2[0]; a3 += v2 * h2[1];
    a0 += v3 * l3[0]; a1 += v3 * l3[1]; a2 += v3 * h3[0]; a3 += v3 * h3[1];
  }
  for (; e < eend; e++) {
    int2 m = epack[e];
    float v = __int_as_float(m.y);
    unsigned int u = base[(size_t)m.x * 64];
    floatx2 lo = __builtin_amdgcn_cvt_pk_f32_fp8(u, false);
    floatx2 hi = __builtin_amdgcn_cvt_pk_f32_fp8(u, true);
    a0 += v * lo[0]; a1 += v * lo[1]; a2 += v * hi[0]; a3 += v * hi[1];
  }
  int c = lane * 4;
  float4 bb = *(const float4*)(b1 + c);
  float4 o;
  o.x = fmaxf(a0 + bb.x, 0.f);
  o.y = fmaxf(a1 + bb.y, 0.f);
  o.z = fmaxf(a2 + bb.z, 0.f);
  o.w = fmaxf(a3 + bb.w, 0.f);
  *(float4*)(mid + (size_t)r * 256 + c) = o;
}

// ---------------- GEMM2: T2p = bf16(mid @ W2), [M][64] (cols 0..39 valid) ----------------
__global__ __launch_bounds__(256) void gemm2_kernel(const float* __restrict__ mid,
                                                    const bf16* __restrict__ W2T,
                                                    bf16* __restrict__ T2p, int M) {
  __shared__ __align__(16) bf16 As[64][40];
  __shared__ __align__(16) bf16 Bs[48][40];
  const int t = threadIdx.x;
  const int wave = t >> 6, lane = t & 63;
  const int quad = lane >> 4, l16 = lane & 15;
  const int m0 = blockIdx.x * 64;
  floatx4 acc[3] = {};
  const int ar = t >> 2, aq = t & 3;
  const int a_gr = m0 + ar;
  const float* a_src = mid + (size_t)a_gr * 256 + aq * 8;

  for (int k0 = 0; k0 < 256; k0 += 32) {
    __syncthreads();
    {
      float4 f0 = {0,0,0,0}, f1 = {0,0,0,0};
      if (a_gr < M) {
        const float4* p = (const float4*)(a_src + k0);
        f0 = p[0]; f1 = p[1];
      }
      bf16x8 av;
      av[0] = (bf16)f0.x; av[1] = (bf16)f0.y; av[2] = (bf16)f0.z; av[3] = (bf16)f0.w;
      av[4] = (bf16)f1.x; av[5] = (bf16)f1.y; av[6] = (bf16)f1.z; av[7] = (bf16)f1.w;
      *(bf16x8*)&As[ar][aq * 8] = av;
    }
    if (t < 192) {
      int n = t >> 2, q = t & 3;
      bf16x8 b = *(const bf16x8*)(W2T + n * 256 + k0 + q * 8);
      *(bf16x8*)&Bs[n][q * 8] = b;
    }
    __syncthreads();
    bf16x8 a = *(const bf16x8*)&As[wave * 16 + l16][quad * 8];
#pragma unroll
    for (int nt = 0; nt < 3; nt++) {
      bf16x8 b = *(const bf16x8*)&Bs[nt * 16 + l16][quad * 8];
      acc[nt] = __builtin_amdgcn_mfma_f32_16x16x32_bf16(a, b, acc[nt], 0, 0, 0);
    }
  }
  const int row_base = m0 + wave * 16 + quad * 4;
#pragma unroll
  for (int nt = 0; nt < 3; nt++) {
#pragma unroll
    for (int j = 0; j < 4; j++) {
      int gr = row_base + j;
      int col = nt * 16 + l16;
      if (gr < M && col < 40) T2p[(size_t)gr * 64 + col] = (bf16)acc[nt][j];
    }
  }
}

// ---------------- SpMM2: out = gather-sum(T2f8) + b2 ----------------
// quarter-wave (16 lanes) per edge, 8 edges per wave-iter; lane q covers
// cols 4q..4q+3 (valid q<10); row = 16 uints (64 B line). shfl-tree combine.
__global__ __launch_bounds__(256) void spmm2_kernel(
    const int* __restrict__ rp, const int2* __restrict__ epack,
    const unsigned int* __restrict__ T2f8, const float* __restrict__ b2,
    float* __restrict__ out2, int M) {
  const int lane = threadIdx.x & 63;
  const int r = blockIdx.x * 4 + (threadIdx.x >> 6);
  if (r >= M) return;
  const int q = lane & 15;
  const int g = lane >> 4;  // edge group 0..3
  const int eend = rp[r];
  int e = (r == 0) ? 0 : rp[r - 1];
  float a0 = 0.f, a1 = 0.f, a2 = 0.f, a3 = 0.f;
  const unsigned int* base = T2f8 + q;  // row stride 16 uints
  if (e < eend && (e & 1)) {  // align to even for int4 loads (group 0 takes it)
    if (g == 0) {
      int2 m = epack[e];
      float v = __int_as_float(m.y);
      unsigned int u = base[(size_t)m.x * 16];
      floatx2 lo = __builtin_amdgcn_cvt_pk_f32_fp8(u, false);
      floatx2 hi = __builtin_amdgcn_cvt_pk_f32_fp8(u, true);
      a0 += v * lo[0]; a1 += v * lo[1]; a2 += v * hi[0]; a3 += v * hi[1];
    }
    e++;
  }
  for (; e + 7 < eend; e += 8) {  // group g: edges e+2g, e+2g+1 via one int4
    int4 m = *(const int4*)(epack + e + 2 * g);
    float v0 = __int_as_float(m.y), v1 = __int_as_float(m.w);
    unsigned int u0 = base[(size_t)m.x * 16];
    unsigned int u1 = base[(size_t)m.z * 16];
    floatx2 l0 = __builtin_amdgcn_cvt_pk_f32_fp8(u0, false);
    floatx2 h0 = __builtin_amdgcn_cvt_pk_f32_fp8(u0, true);
    floatx2 l1 = __builtin_amdgcn_cvt_pk_f32_fp8(u1, false);
    floatx2 h1 = __builtin_amdgcn_cvt_pk_f32_fp8(u1, true);
    a0 += v0 * l0[0]; a1 += v0 * l0[1]; a2 += v0 * h0[0]; a3 += v0 * h0[1];
    a0 += v1 * l1[0]; a1 += v1 * l1[1]; a2 += v1 * h1[0]; a3 += v1 * h1[1];
  }
  for (; e + 3 < eend; e += 4) {  // group g: edge e+g
    int2 m = epack[e + g];
    float v = __int_as_float(m.y);
    unsigned int u = base[(size_t)m.x * 16];
    floatx2 lo = __builtin_amdgcn_cvt_pk_f32_fp8(u, false);
    floatx2 hi = __builtin_amdgcn_cvt_pk_f32_fp8(u, true);
    a0 += v * lo[0]; a1 += v * lo[1]; a2 += v * hi[0]; a3 += v * hi[1];
  }
  if (e + g < eend) {  // tail: groups 0..(eend-e-1)
    int2 m = epack[e + g];
    float v = __int_as_float(m.y);
    unsigned int u = base[(size_t)m.x * 16];
    floatx2 lo = __builtin_amdgcn_cvt_pk_f32_fp8(u, false);
    floatx2 hi = __builtin_amdgcn_cvt_pk_f32_fp8(u, true);
    a0 += v * lo[0]; a1 += v * lo[1]; a2 += v * hi[0]; a3 += v * hi[1];
  }
  a0 += __shfl_down(a0, 32, 64); a0 += __shfl_down(a0, 16, 64);
  a1 += __shfl_down(a1, 32, 64); a1 += __shfl_down(a1, 16, 64);
  a2 += __shfl_down(a2, 32, 64); a2 += __shfl_down(a2, 16, 64);
  a3 += __shfl_down(a3, 32, 64); a3 += __shfl_down(a3, 16, 64);
  if (lane < 10) {
    int c = lane * 4;
    float4 o;
    o.x = a0 + b2[c];
    o.y = a1 + b2[c + 1];
    o.z = a2 + b2[c + 2];
    o.w = a3 + b2[c + 3];
    *(float4*)(out2 + (size_t)r * 40 + c) = o;
  }
}

// ---------------- launch ----------------
extern "C" void kernel_launch(void* const* d_in, const int* in_sizes, int n_in,
                              void* d_out, int out_size, void* d_ws, size_t ws_size,
                              hipStream_t stream) {
  const float* x        = (const float*)d_in[0];
  const int*   edge_row = (const int*)d_in[1];
  const int*   edge_col = (const int*)d_in[2];
  const float* edge_val = (const float*)d_in[3];
  const float* W1       = (const float*)d_in[4];
  const float* b1       = (const float*)d_in[5];
  const float* W2       = (const float*)d_in[6];
  const float* b2       = (const float*)d_in[7];
  const int M = in_sizes[0] / 512;  // 100000 nodes
  const int E = in_sizes[1];        // 3200000 edges
  const int NB = (M + 255) >> 8;    // 391 buckets
  const int EBLK = (E + 8191) / 8192;  // 391 blocks

  char* ws = (char*)d_ws;
  size_t off = 0;
  bf16* T1      = (bf16*)(ws + off);  off += (size_t)M * 256 * 2;
  bf16* W1T     = (bf16*)(ws + off);  off += 512 * 256 * 2;
  bf16* W2T     = (bf16*)(ws + off);  off += 48 * 256 * 2;
  bf16* T2p     = (bf16*)(ws + off);  off += (size_t)M * 64 * 2;
  unsigned int* T1f8 = (unsigned int*)(ws + off); off += (size_t)M * 256;
  unsigned int* T2f8 = (unsigned int*)(ws + off); off += (size_t)M * 64;
  int* rp       = (int*)(ws + off);   off += (size_t)M * 4;
  int* gbcount  = (int*)(ws + off);   off += NBMAX * 4;
  int* bstart   = (int*)(ws + off);   off += (NBMAX + 1) * 4;
  int* blkcnt   = (int*)(ws + off);   off += (size_t)NB * EBLK * 4;
  int* blkoff   = (int*)(ws + off);   off += (size_t)NB * EBLK * 4;
  off = (off + 15) & ~(size_t)15;
  int2* epack_f = (int2*)(ws + off);  off += (size_t)E * 8;
  int2* epack_b = (int2*)T1;          // alias: used only before gemm1 writes T1

  float* mid  = (float*)d_out;
  float* out2 = mid + (size_t)M * 256;

  hipMemsetAsync(gbcount, 0, NBMAX * 4, stream);
  conv_w<<<(512 * 256 + 48 * 256 + 255) / 256, 256, 0, stream>>>(W1, W2, W1T, W2T);
  bhist_kernel<<<EBLK, 256, 0, stream>>>(edge_row, gbcount, blkcnt, E, NB, EBLK);
  bscan_kernel<<<1, 512, 0, stream>>>(gbcount, bstart, NB);
  bscan2_kernel<<<NB, 512, 0, stream>>>(blkcnt, bstart, blkoff, EBLK);
  partA_kernel<<<EBLK, 256, 0, stream>>>(edge_row, edge_col, edge_val,
                                         blkoff, epack_b, E, NB, EBLK);
  partB_kernel<<<NB, 256, 0, stream>>>(epack_b, bstart, epack_f, rp, M);
  gemm1_kernel<<<(M + 63) / 64, 256, 0, stream>>>(x, W1T, T1, M);
  {
    int n8 = M * 256 / 8;
    cvt_fp8_kernel<<<(n8 + 255) / 256, 256, 0, stream>>>((const unsigned int*)T1,
                                                         T1f8, n8);
  }
  spmm1_kernel<<<(M + 3) / 4, 256, 0, stream>>>(rp, epack_f, T1f8, b1, mid, M);
  gemm2_kernel<<<(M + 63) / 64, 256, 0, stream>>>(mid, W2T, T2p, M);
  {
    int n8 = M * 64 / 8;
    cvt_fp8_kernel<<<(n8 + 255) / 256, 256, 0, stream>>>((const unsigned int*)T2p,
                                                         T2f8, n8);
  }
  spmm2_kernel<<<(M + 3) / 4, 256, 0, stream>>>(rp, epack_f, T2f8, b2, out2, M);
}